// Round 3
// baseline (77.827 us; speedup 1.0000x reference)
//
#include <hip/hip_runtime.h>

constexpr int EMB    = 300;
constexpr int EMB4   = 75;    // EMB / 4 (float4 chunks per row)
constexpr int HIDDEN = 512;
constexpr int SEQ    = 512;
constexpr int BATCH  = 1024;
constexpr int GB     = 2;     // batch rows per block in MLP kernel
constexpr int NSG    = 4;     // seq sub-groups inside a pool block

__device__ __forceinline__ float4 f4add(float4 a, float4 b) {
    return make_float4(a.x + b.x, a.y + b.y, a.z + b.z, a.w + b.w);
}

// ---------------- Kernel T: transpose text [S,B] -> textT [B,S] ---------------
__global__ __launch_bounds__(256) void transpose_kernel(
    const int* __restrict__ text, int* __restrict__ textT)
{
    __shared__ int tile[32][33];
    const int s0 = blockIdx.x * 32;
    const int b0 = blockIdx.y * 32;
    const int tx = threadIdx.x;        // 0..31
    const int ty = threadIdx.y;        // 0..7
#pragma unroll
    for (int k = 0; k < 32; k += 8)
        tile[ty + k][tx] = text[(size_t)(s0 + ty + k) * BATCH + (b0 + tx)];
    __syncthreads();
#pragma unroll
    for (int k = 0; k < 32; k += 8)
        textT[(size_t)(b0 + ty + k) * SEQ + (s0 + tx)] = tile[tx][ty + k];
}

// ---------------- Kernel A: embedding gather + masked mean pool (partial) ----
// Grid (BATCH, NS). Block (b,h) handles its segment of row b's tokens.
// 320 threads: 4 seq-groups x 75 float4-lanes. Inner loop issues 8 INDEPENDENT
// float4 loads into named temps (128 B in flight per thread) before a tree
// accumulate — forces the compiler to keep all 8 loads outstanding.
__global__ __launch_bounds__(320) void pool_kernel(
    const int* __restrict__ textT,     // [BATCH, SEQ]
    const int* __restrict__ lengths,   // [BATCH]
    const float* __restrict__ emb,     // [VOCAB, EMB]
    float* __restrict__ part,          // [NS, BATCH, EMB]
    int NS)
{
    const int b     = blockIdx.x;
    const int h     = blockIdx.y;
    const int len   = lengths[b];
    const int chunk = (len + NS - 1) / NS;
    const int s0    = h * chunk;
    const int n     = max(0, min(len, s0 + chunk) - s0);

    __shared__ int    toks[SEQ];
    __shared__ float4 red[NSG][EMB4];

    for (int t = threadIdx.x; t < n; t += 320)
        toks[t] = textT[(size_t)b * SEQ + s0 + t];   // coalesced, contiguous
    __syncthreads();

    const int t = threadIdx.x;
    if (t < NSG * EMB4) {
        const int g = t / EMB4;   // seq group 0..3
        const int c = t % EMB4;   // float4 chunk 0..74
        float4 a0 = make_float4(0.f, 0.f, 0.f, 0.f);
        float4 a1 = a0, a2 = a0, a3 = a0;
        int i = g;
        for (; i + 28 < n; i += 32) {   // 8 rows per iteration, stride NSG=4
            const float4 v0 = ((const float4*)(emb + (size_t)toks[i +  0] * EMB))[c];
            const float4 v1 = ((const float4*)(emb + (size_t)toks[i +  4] * EMB))[c];
            const float4 v2 = ((const float4*)(emb + (size_t)toks[i +  8] * EMB))[c];
            const float4 v3 = ((const float4*)(emb + (size_t)toks[i + 12] * EMB))[c];
            const float4 v4 = ((const float4*)(emb + (size_t)toks[i + 16] * EMB))[c];
            const float4 v5 = ((const float4*)(emb + (size_t)toks[i + 20] * EMB))[c];
            const float4 v6 = ((const float4*)(emb + (size_t)toks[i + 24] * EMB))[c];
            const float4 v7 = ((const float4*)(emb + (size_t)toks[i + 28] * EMB))[c];
            a0 = f4add(a0, v0);
            a1 = f4add(a1, v1);
            a2 = f4add(a2, v2);
            a3 = f4add(a3, v3);
            a0 = f4add(a0, v4);
            a1 = f4add(a1, v5);
            a2 = f4add(a2, v6);
            a3 = f4add(a3, v7);
        }
        for (; i < n; i += 4) {
            const float4 v = ((const float4*)(emb + (size_t)toks[i] * EMB))[c];
            a0 = f4add(a0, v);
        }
        red[g][c] = f4add(f4add(a0, a1), f4add(a2, a3));
    }
    __syncthreads();

    if (t < EMB4) {
        const float4 s = f4add(f4add(red[0][t], red[1][t]),
                               f4add(red[2][t], red[3][t]));
        float4* dst = (float4*)(part + ((size_t)h * BATCH + b) * EMB);
        dst[t] = s;   // zeros for empty segments (determinism + correctness)
    }
}

// ---------------- Kernel B: combine partials + fc1 + relu + fc2 ----------------
// GB=2 -> 512 blocks (2 per CU for barrier overlap). e-loop step 10 keeps
// 10 coalesced W1 loads in flight; pT reads are wave-uniform LDS broadcasts.
__global__ __launch_bounds__(512) void mlp_kernel(
    const float* __restrict__ part,    // [NS, BATCH, EMB]
    const int* __restrict__ lengths,   // [BATCH]
    const float* __restrict__ W1,      // [EMB, HIDDEN]
    const float* __restrict__ b1,      // [HIDDEN]
    const float* __restrict__ W2,      // [HIDDEN, 2]
    const float* __restrict__ b2,      // [2]
    float* __restrict__ out,           // [BATCH, 2]
    int NS)
{
    __shared__ float2 pT[EMB];           // [e] -> (row b0, row b0+1)
    __shared__ float  h[GB][HIDDEN];

    const int b0  = blockIdx.x * GB;
    const int tid = threadIdx.x;

    // stage: combine NS partials, scale by 1/len, store interleaved (g fastest)
    float* pTf = (float*)pT;
    for (int i = tid; i < EMB * GB; i += 512) {
        const int g = i / EMB;
        const int e = i - g * EMB;
        float s = 0.f;
        for (int ns = 0; ns < NS; ++ns)
            s += part[((size_t)ns * BATCH + b0 + g) * EMB + e];
        pTf[e * GB + g] = s / (float)lengths[b0 + g];
    }
    __syncthreads();

    // fc1 + relu: thread j computes h[g][j] for g=0..1; 10 W1 loads in flight
    const int j = tid;                   // HIDDEN == blockDim
    const float bias1 = b1[j];
    float2 acc = make_float2(bias1, bias1);
    for (int e = 0; e < EMB; e += 10) {  // 300 = 30 * 10, exact
        const float w0 = W1[(e + 0) * HIDDEN + j];
        const float w1 = W1[(e + 1) * HIDDEN + j];
        const float w2 = W1[(e + 2) * HIDDEN + j];
        const float w3 = W1[(e + 3) * HIDDEN + j];
        const float w4 = W1[(e + 4) * HIDDEN + j];
        const float w5 = W1[(e + 5) * HIDDEN + j];
        const float w6 = W1[(e + 6) * HIDDEN + j];
        const float w7 = W1[(e + 7) * HIDDEN + j];
        const float w8 = W1[(e + 8) * HIDDEN + j];
        const float w9 = W1[(e + 9) * HIDDEN + j];
        const float2 p0 = pT[e + 0];
        const float2 p1 = pT[e + 1];
        const float2 p2 = pT[e + 2];
        const float2 p3 = pT[e + 3];
        const float2 p4 = pT[e + 4];
        const float2 p5 = pT[e + 5];
        const float2 p6 = pT[e + 6];
        const float2 p7 = pT[e + 7];
        const float2 p8 = pT[e + 8];
        const float2 p9 = pT[e + 9];
        acc.x += p0.x * w0 + p1.x * w1 + p2.x * w2 + p3.x * w3 + p4.x * w4
               + p5.x * w5 + p6.x * w6 + p7.x * w7 + p8.x * w8 + p9.x * w9;
        acc.y += p0.y * w0 + p1.y * w1 + p2.y * w2 + p3.y * w3 + p4.y * w4
               + p5.y * w5 + p6.y * w6 + p7.y * w7 + p8.y * w8 + p9.y * w9;
    }
    h[0][j] = fmaxf(acc.x, 0.f);
    h[1][j] = fmaxf(acc.y, 0.f);
    __syncthreads();

    // fc2: wave g (g < GB) reduces batch row b0+g
    const int wave = tid >> 6;
    const int lane = tid & 63;
    if (wave < GB) {
        float s0 = 0.f, s1 = 0.f;
        for (int jj = lane; jj < HIDDEN; jj += 64) {
            const float  hv = h[wave][jj];
            const float2 w  = *(const float2*)&W2[jj * 2];
            s0 += hv * w.x;
            s1 += hv * w.y;
        }
#pragma unroll
        for (int off = 32; off > 0; off >>= 1) {
            s0 += __shfl_down(s0, off);
            s1 += __shfl_down(s1, off);
        }
        if (lane == 0) {
            out[(b0 + wave) * 2 + 0] = s0 + b2[0];
            out[(b0 + wave) * 2 + 1] = s1 + b2[1];
        }
    }
}

extern "C" void kernel_launch(void* const* d_in, const int* in_sizes, int n_in,
                              void* d_out, int out_size, void* d_ws, size_t ws_size,
                              hipStream_t stream) {
    const int*   text    = (const int*)d_in[0];
    const int*   lengths = (const int*)d_in[1];
    const float* emb     = (const float*)d_in[2];
    const float* W1      = (const float*)d_in[3];
    const float* b1      = (const float*)d_in[4];
    const float* W2      = (const float*)d_in[5];
    const float* b2      = (const float*)d_in[6];
    float*       out     = (float*)d_out;

    int*   textT = (int*)d_ws;                                  // 2 MB
    const size_t textBytes = (size_t)SEQ * BATCH * sizeof(int);
    float* part  = (float*)((char*)d_ws + textBytes);
    const size_t poolBytes = (size_t)BATCH * EMB * sizeof(float);
    const size_t avail = (ws_size > textBytes) ? ws_size - textBytes : 0;
    const int NS = (avail >= 8 * poolBytes) ? 8
                 : (avail >= 4 * poolBytes) ? 4
                 : (avail >= 2 * poolBytes) ? 2 : 1;

    transpose_kernel<<<dim3(SEQ / 32, BATCH / 32), dim3(32, 8), 0, stream>>>(text, textT);
    pool_kernel<<<dim3(BATCH, NS), 320, 0, stream>>>(textT, lengths, emb, part, NS);
    mlp_kernel<<<BATCH / GB, 512, 0, stream>>>(part, lengths, W1, b1, W2, b2, out, NS);
}